// Round 1
// 3098.076 us; speedup vs baseline: 1.0296x; 1.0296x over previous
//
#include <hip/hip_runtime.h>
#include <hip/hip_bf16.h>
#include <stdint.h>

// ---------- types / helpers ----------
typedef short bf16x8 __attribute__((ext_vector_type(8)));
typedef float f32x4  __attribute__((ext_vector_type(4)));

#define MFMA16(a, b, c) __builtin_amdgcn_mfma_f32_16x16x32_bf16((a), (b), (c), 0, 0, 0)

__device__ __forceinline__ unsigned short f2bf(float x) {
  union { float f; unsigned int u; } v; v.f = x;
  unsigned int u = v.u;
  unsigned int r = (u + 0x7FFFu + ((u >> 16) & 1u)) >> 16;  // RNE
  return (unsigned short)r;
}

__device__ __forceinline__ bf16x8 pack8(const float* __restrict__ p) {
  bf16x8 r;
#pragma unroll
  for (int i = 0; i < 8; i++) r[i] = (short)f2bf(p[i]);
  return r;
}

__device__ __forceinline__ bf16x8 ldb8(const unsigned short* __restrict__ p) {
  return *(const bf16x8*)p;
}

__device__ __forceinline__ float sigm(float x) { return 1.0f / (1.0f + expf(-x)); }

// LLC-bypassing (agent-scope) 4-byte ops: performed at the device coherence
// point, so no buffer_wbl2 (release flush) / per-poll buffer_inv is needed.
__device__ __forceinline__ void st_agent(unsigned int* p, unsigned int v) {
  __hip_atomic_store(p, v, __ATOMIC_RELAXED, __HIP_MEMORY_SCOPE_AGENT);
}
__device__ __forceinline__ unsigned int ld_agent(const unsigned int* p) {
  return __hip_atomic_load(p, __ATOMIC_RELAXED, __HIP_MEMORY_SCOPE_AGENT);
}

// ---------- K1: per-batch ht + vbias ----------
__global__ void k_prep(const int* __restrict__ timestep, const float* __restrict__ tc_W1,
                       const float* __restrict__ tc_b1, const float* __restrict__ tc_W2,
                       const float* __restrict__ tc_b2, const float* __restrict__ trans_b,
                       float* __restrict__ ht, float* __restrict__ vbias) {
  __shared__ float h1l[64];
  __shared__ float htl[64];
  int b = blockIdx.x, j = threadIdx.x;
  float ts = (float)timestep[b] / 100.0f;
  h1l[j] = tanhf(ts * tc_W1[j] + tc_b1[j]);
  __syncthreads();
  float s = tc_b2[j];
  for (int m = 0; m < 64; m++) s += tc_W2[j * 64 + m] * h1l[m];
  float h = tanhf(s);
  htl[j] = h;
  ht[b * 64 + j] = h;
  __syncthreads();
  float vb = 0.f;
  for (int m = 0; m < 64; m++) vb += trans_b[j * 64 + m] * htl[m];
  vbias[b * 64 + j] = vb;
}

// ---------- K2: M[b][i][k] = sum_j ht[b][j] * trans_W[(i*64+j)*512 + k] ----------
__global__ void k_M(const float* __restrict__ trans_W, const float* __restrict__ ht,
                    float* __restrict__ M) {
  __shared__ float htl[4][64];
  int i = blockIdx.x;        // 0..63
  int b0 = blockIdx.y * 4;   // 8 chunks of 4 batches
  int tid = threadIdx.x;     // 512 threads = k
  if (tid < 256) htl[tid >> 6][tid & 63] = ht[(b0 + (tid >> 6)) * 64 + (tid & 63)];
  __syncthreads();
  int k = tid;
  float acc[4] = {0.f, 0.f, 0.f, 0.f};
  for (int j = 0; j < 64; j++) {
    float w = trans_W[(i * 64 + j) * 512 + k];
#pragma unroll
    for (int bb = 0; bb < 4; bb++) acc[bb] += htl[bb][j] * w;
  }
#pragma unroll
  for (int bb = 0; bb < 4; bb++) M[((b0 + bb) * 64 + i) * 512 + k] = acc[bb];
}

// ---------- K3: vec[n][i] = sum_k M[b][i][k]*U[text[n]][k] + vbias[b][i]  (bf16 out) ----------
__global__ void k_vec(const int* __restrict__ text, const float* __restrict__ U,
                      const float* __restrict__ M, const float* __restrict__ vbias,
                      unsigned short* __restrict__ vec) {
  __shared__ float el[16][512];
  int b = blockIdx.x, sc = blockIdx.y, tid = threadIdx.x;
  for (int idx = tid; idx < 16 * 512; idx += 256) {
    int ss = idx >> 9, k = idx & 511;
    int tok = text[(sc * 16 + ss) * 32 + b];
    el[ss][k] = U[tok * 512 + k];
  }
  __syncthreads();
  int i = tid & 63, sg = tid >> 6;
  float acc[4] = {0.f, 0.f, 0.f, 0.f};
  const float* Mr = M + (b * 64 + i) * 512;
  for (int k = 0; k < 512; k++) {
    float m = Mr[k];
#pragma unroll
    for (int st = 0; st < 4; st++) acc[st] += m * el[sg * 4 + st][k];
  }
  float vb = vbias[b * 64 + i];
#pragma unroll
  for (int st = 0; st < 4; st++) {
    int s = sc * 16 + sg * 4 + st;
    vec[(s * 32 + b) * 64 + i] = f2bf(acc[st] + vb);
  }
}

// ---------- K4: A0[g][i] = Wih0[g]·dw_W[:,i];  c0[g] = Wih0[g]·dw_b + bih0[g] + bhh0[g] ----------
__global__ void k_A0(const float* __restrict__ Wih0, const float* __restrict__ dw_W,
                     const float* __restrict__ dw_b, const float* __restrict__ bih0,
                     const float* __restrict__ bhh0, float* __restrict__ A0,
                     float* __restrict__ c0) {
  int tid = threadIdx.x;
  int wave = tid >> 6, lane = tid & 63;
  for (int gg = 0; gg < 16; gg++) {
    int g = blockIdx.x * 64 + wave * 16 + gg;
    const float* wr = Wih0 + g * 512;
    float acc = 0.f;
    for (int e = 0; e < 512; e++) acc += wr[e] * dw_W[e * 64 + lane];
    A0[g * 64 + lane] = acc;
    float p = 0.f;
#pragma unroll
    for (int e8 = 0; e8 < 8; e8++) { int e = e8 * 64 + lane; p += wr[e] * dw_b[e]; }
#pragma unroll
    for (int off = 32; off > 0; off >>= 1) p += __shfl_down(p, off);
    if (lane == 0) c0[g] = p + bih0[g] + bhh0[g];
  }
}

// ---------- K5: persistent pipelined 2-layer LSTM ----------
// Sync redesign vs previous version:
//  * per-block flag (dense uint array), posted with ONE relaxed agent-scope
//    (LLC-bypass) store per block per step -> no contended RMW, no wbl2.
//  * all h/out stores are paired 4-byte agent-scope stores (write-through to
//    LLC) -> nothing dirty in L2, __syncthreads' vmcnt drain orders them
//    before the flag post.
//  * wave-parallel polling: lane i polls flag[i] with relaxed (bypassing)
//    loads + __all, then ONE acquire fence (single buffer_inv) per wave per
//    step instead of one per poll iteration.
//  * A-fragments fully prefetched after the fence (one LLC latency per step);
//    vec fragments prefetched before the wait, consumed after the h-MFMAs
//    (baseline accumulation order preserved bitwise).
//  * layer1 polls split by wave role: waves 0-1 gate on flag0 (layer0 output,
//    usually already posted - layer0 free-runs ahead), waves 2-3 on flag1.
__global__ void __launch_bounds__(256, 1)
k_lstm(const unsigned short* __restrict__ vec, const float* __restrict__ A0,
       const float* __restrict__ c0, const float* __restrict__ Whh0,
       const float* __restrict__ Wih1, const float* __restrict__ Whh1,
       const float* __restrict__ bih1, const float* __restrict__ bhh1,
       unsigned short* __restrict__ h0buf, unsigned short* __restrict__ h1buf,
       unsigned short* __restrict__ out0, unsigned short* __restrict__ out1,
       unsigned int* __restrict__ flag0, unsigned int* __restrict__ flag1) {
  __shared__ float exch[4][32][67];  // +3 pad: breaks bank conflicts on exchange
  const int tid = threadIdx.x;
  const int wave = tid >> 6, lane = tid & 63;
  const int l15 = lane & 15, quad = lane >> 4;
  const int blk = blockIdx.x;
  const f32x4 fzero = {0.f, 0.f, 0.f, 0.f};
  const unsigned int SPIN_MAX = 1u << 16;  // safety valve: wrong-answer beats hang

  if (blk < 64) {
    // ================= layer 0 =================
    const int colbase = blk * 16;
    bf16x8 bh[4][8];  // Whh0 frags: [gate n-tile][local kstep]; wave w covers ksteps w*8..w*8+7
    bf16x8 bv[4];     // A0 frags (K=64): wave0 k 0..31, wave1 k 32..63
#pragma unroll
    for (int nt = 0; nt < 4; nt++) {
      int row = nt * 1024 + colbase + l15;
      const float* wr = Whh0 + row * 1024;
#pragma unroll
      for (int s8 = 0; s8 < 8; s8++) {
        int k = (wave * 8 + s8) * 32 + quad * 8;
        bh[nt][s8] = pack8(wr + k);
      }
      if (wave < 2) bv[nt] = pack8(A0 + row * 64 + wave * 32 + quad * 8);
    }
    // elementwise ownership: thread -> (batch eb, hcol pair 2*ehp, 2*ehp+1)
    const int eb = tid >> 3, ehp = tid & 7;
    float c0v[2][4];
#pragma unroll
    for (int p = 0; p < 2; p++)
#pragma unroll
      for (int g = 0; g < 4; g++) c0v[p][g] = c0[g * 1024 + colbase + 2 * ehp + p];
    float cst[2] = {0.f, 0.f};

    for (int t = 0; t < 128; t++) {
      // prefetch vec frags (step-constant, no coherence concern) before the wait
      bf16x8 va0, va1;
      if (wave < 2) {
        int k = wave * 32 + quad * 8;
        const unsigned short* vp = vec + (t * 32) * 64;
        va0 = ldb8(vp + l15 * 64 + k);
        va1 = ldb8(vp + (16 + l15) * 64 + k);
      }
      if (t > 0) {
        // all 64 layer0 blocks must have finished step t-1
        unsigned int tgt = (unsigned int)t, it = 0;
        while (true) {
          unsigned int v = ld_agent(&flag0[lane]);
          if (__all((int)(v >= tgt))) break;
          if (++it > SPIN_MAX) break;
        }
        __builtin_amdgcn_fence(__ATOMIC_ACQUIRE, "agent");
      }
      const unsigned short* hb = h0buf + (t & 1) * 32768;
      // full A prefetch: 16 independent loads in flight -> one LLC latency
      bf16x8 ah0[8], ah1[8];
#pragma unroll
      for (int s8 = 0; s8 < 8; s8++) {
        int k = (wave * 8 + s8) * 32 + quad * 8;
        ah0[s8] = ldb8(hb + l15 * 1024 + k);
        ah1[s8] = ldb8(hb + (16 + l15) * 1024 + k);
      }
      f32x4 acc[2][4];
#pragma unroll
      for (int mt = 0; mt < 2; mt++)
#pragma unroll
        for (int nt = 0; nt < 4; nt++) acc[mt][nt] = fzero;
#pragma unroll
      for (int s8 = 0; s8 < 8; s8++)
#pragma unroll
        for (int nt = 0; nt < 4; nt++) {
          acc[0][nt] = MFMA16(ah0[s8], bh[nt][s8], acc[0][nt]);
          acc[1][nt] = MFMA16(ah1[s8], bh[nt][s8], acc[1][nt]);
        }
      if (wave < 2) {  // vec contribution (K=64) - kept AFTER h-MFMAs (baseline FP order)
#pragma unroll
        for (int nt = 0; nt < 4; nt++) {
          acc[0][nt] = MFMA16(va0, bv[nt], acc[0][nt]);
          acc[1][nt] = MFMA16(va1, bv[nt], acc[1][nt]);
        }
      }
#pragma unroll
      for (int mt = 0; mt < 2; mt++)
#pragma unroll
        for (int nt = 0; nt < 4; nt++)
#pragma unroll
          for (int r = 0; r < 4; r++)
            exch[wave][mt * 16 + quad * 4 + r][nt * 16 + l15] = acc[mt][nt][r];
      __syncthreads();

      unsigned short hv[2];
#pragma unroll
      for (int p = 0; p < 2; p++) {
        int hcol = 2 * ehp + p;
        float g4[4];
#pragma unroll
        for (int g = 0; g < 4; g++) {
          int col = g * 16 + hcol;
          g4[g] = exch[0][eb][col] + exch[1][eb][col] + exch[2][eb][col] + exch[3][eb][col] + c0v[p][g];
        }
        float ii = sigm(g4[0]), ff = sigm(g4[1]), gg = tanhf(g4[2]), oo = sigm(g4[3]);
        cst[p] = ff * cst[p] + ii * gg;
        float h = oo * tanhf(cst[p]);
        hv[p] = f2bf(h);
      }
      unsigned int packed = (unsigned int)hv[0] | ((unsigned int)hv[1] << 16);
      int off = eb * 1024 + colbase + 2 * ehp;
      st_agent((unsigned int*)(h0buf + ((t + 1) & 1) * 32768 + off), packed);
      st_agent((unsigned int*)(out0 + (t * 32) * 1024 + off), packed);
      __syncthreads();  // drains all waves' stores (vmcnt 0) before the post
      if (tid == 0) st_agent(&flag0[blk], (unsigned int)(t + 1));
    }
  } else {
    // ================= layer 1 =================
    const int blk1 = blk - 64;
    const int colbase = blk1 * 8;  // 8 h-cols -> 32 gate-cols (gate = c>>3, hcol = c&7)
    bf16x8 bfr[2][16];  // wave w covers ksteps w*16..w*16+15 of 64 (s<32: Wih1, s>=32: Whh1)
#pragma unroll
    for (int nt = 0; nt < 2; nt++) {
      int c = nt * 16 + l15;
      int row = (c >> 3) * 1024 + colbase + (c & 7);
#pragma unroll
      for (int ls = 0; ls < 16; ls++) {
        int s = wave * 16 + ls;
        const float* W = (s < 32) ? Wih1 : Whh1;
        int k = ((s < 32) ? s : (s - 32)) * 32 + quad * 8;
        bfr[nt][ls] = pack8(W + row * 1024 + k);
      }
    }
    // elementwise ownership (threads 0..127): (batch eb, hcol pair 2*ehp, 2*ehp+1)
    const int eb = tid >> 2, ehp = tid & 3;
    float b1v[2][4];
    float cst[2] = {0.f, 0.f};
    if (tid < 128) {
#pragma unroll
      for (int p = 0; p < 2; p++)
#pragma unroll
        for (int g = 0; g < 4; g++) {
          int row = g * 1024 + colbase + 2 * ehp + p;
          b1v[p][g] = bih1[row] + bhh1[row];
        }
    }

    for (int t = 0; t < 128; t++) {
      const unsigned short* Asrc;
      if (wave < 2) {
        // out0 K-half: gate on layer0 having finished step t
        unsigned int tgt = (unsigned int)(t + 1), it = 0;
        while (true) {
          unsigned int v = ld_agent(&flag0[lane]);
          if (__all((int)(v >= tgt))) break;
          if (++it > SPIN_MAX) break;
        }
        __builtin_amdgcn_fence(__ATOMIC_ACQUIRE, "agent");
        Asrc = out0 + (t * 32) * 1024;
      } else {
        // h1 K-half: gate on all layer1 blocks having finished step t-1
        if (t > 0) {
          unsigned int tgt = (unsigned int)t, it = 0;
          while (true) {
            unsigned int v0 = ld_agent(&flag1[lane]);
            unsigned int v1 = ld_agent(&flag1[64 + lane]);
            if (__all((int)((v0 >= tgt) & (v1 >= tgt)))) break;
            if (++it > SPIN_MAX) break;
          }
          __builtin_amdgcn_fence(__ATOMIC_ACQUIRE, "agent");
        }
        Asrc = h1buf + (t & 1) * 32768;
      }
      f32x4 acc[2][2];
      acc[0][0] = fzero; acc[0][1] = fzero; acc[1][0] = fzero; acc[1][1] = fzero;
      // two batches of 8 ksteps: 16 loads in flight, then their 32 MFMAs
#pragma unroll
      for (int hb8 = 0; hb8 < 2; hb8++) {
        bf16x8 a0[8], a1[8];
#pragma unroll
        for (int l8 = 0; l8 < 8; l8++) {
          int s = wave * 16 + hb8 * 8 + l8;
          int k = ((s < 32) ? s : (s - 32)) * 32 + quad * 8;
          a0[l8] = ldb8(Asrc + l15 * 1024 + k);
          a1[l8] = ldb8(Asrc + (16 + l15) * 1024 + k);
        }
#pragma unroll
        for (int l8 = 0; l8 < 8; l8++) {
          int ls = hb8 * 8 + l8;
#pragma unroll
          for (int nt = 0; nt < 2; nt++) {
            acc[0][nt] = MFMA16(a0[l8], bfr[nt][ls], acc[0][nt]);
            acc[1][nt] = MFMA16(a1[l8], bfr[nt][ls], acc[1][nt]);
          }
        }
      }
#pragma unroll
      for (int mt = 0; mt < 2; mt++)
#pragma unroll
        for (int nt = 0; nt < 2; nt++)
#pragma unroll
          for (int r = 0; r < 4; r++)
            exch[wave][mt * 16 + quad * 4 + r][nt * 16 + l15] = acc[mt][nt][r];
      __syncthreads();

      if (tid < 128) {
        unsigned short hv[2];
#pragma unroll
        for (int p = 0; p < 2; p++) {
          int hcol = 2 * ehp + p;
          float g4[4];
#pragma unroll
          for (int g = 0; g < 4; g++) {
            int col = g * 8 + hcol;
            g4[g] = exch[0][eb][col] + exch[1][eb][col] + exch[2][eb][col] + exch[3][eb][col] + b1v[p][g];
          }
          float ii = sigm(g4[0]), ff = sigm(g4[1]), gg = tanhf(g4[2]), oo = sigm(g4[3]);
          cst[p] = ff * cst[p] + ii * gg;
          float h = oo * tanhf(cst[p]);
          hv[p] = f2bf(h);
        }
        unsigned int packed = (unsigned int)hv[0] | ((unsigned int)hv[1] << 16);
        int off = eb * 1024 + colbase + 2 * ehp;
        st_agent((unsigned int*)(h1buf + ((t + 1) & 1) * 32768 + off), packed);
        st_agent((unsigned int*)(out1 + (t * 32) * 1024 + off), packed);
      }
      __syncthreads();
      if (tid == 0) st_agent(&flag1[blk1], (unsigned int)(t + 1));
    }
  }
}

// ---------- K6: decode logits = out1 @ dec_W.T + dec_b  (bf16 MFMA, fp32 out) ----------
// grid(32 M-tiles, 250 N-tiles): x-fastest so 32 consecutive blocks share one dec_W tile (L2 reuse).
__global__ void __launch_bounds__(256)
k_dec(const unsigned short* __restrict__ out1, const float* __restrict__ dec_W,
      const float* __restrict__ dec_b, float* __restrict__ out) {
  __shared__ unsigned short As[128][72];  // +8 pad: 2-way LDS banking only
  __shared__ unsigned short Bs[128][72];
  const int tid = threadIdx.x;
  const int wave = tid >> 6, lane = tid & 63;
  const int l15 = lane & 15, quad = lane >> 4;
  const int wm = wave & 1, wn = wave >> 1;
  const int mbase = blockIdx.x * 128;
  const int nbase = blockIdx.y * 128;
  const f32x4 fzero = {0.f, 0.f, 0.f, 0.f};
  f32x4 acc[4][4];
#pragma unroll
  for (int a = 0; a < 4; a++)
#pragma unroll
    for (int b = 0; b < 4; b++) acc[a][b] = fzero;

  for (int k0 = 0; k0 < 1024; k0 += 64) {
#pragma unroll
    for (int h = 0; h < 4; h++) {
      int slot = tid + h * 256;          // [0,1024): 128 rows x 8 chunks
      int r = slot >> 3, c8 = (slot & 7) * 8;
      *(bf16x8*)&As[r][c8] = ldb8(out1 + (mbase + r) * 1024 + k0 + c8);
      *(bf16x8*)&Bs[r][c8] = pack8(dec_W + (nbase + r) * 1024 + k0 + c8);
    }
    __syncthreads();
#pragma unroll
    for (int ks = 0; ks < 2; ks++) {
      bf16x8 af[4], bf[4];
#pragma unroll
      for (int mt = 0; mt < 4; mt++) af[mt] = *(const bf16x8*)&As[wm * 64 + mt * 16 + l15][ks * 32 + quad * 8];
#pragma unroll
      for (int nt = 0; nt < 4; nt++) bf[nt] = *(const bf16x8*)&Bs[wn * 64 + nt * 16 + l15][ks * 32 + quad * 8];
#pragma unroll
      for (int mt = 0; mt < 4; mt++)
#pragma unroll
        for (int nt = 0; nt < 4; nt++) acc[mt][nt] = MFMA16(af[mt], bf[nt], acc[mt][nt]);
    }
    __syncthreads();
  }
#pragma unroll
  for (int mt = 0; mt < 4; mt++)
#pragma unroll
    for (int nt = 0; nt < 4; nt++)
#pragma unroll
      for (int r = 0; r < 4; r++) {
        int row = mbase + wm * 64 + mt * 16 + quad * 4 + r;
        int col = nbase + wn * 64 + nt * 16 + l15;
        out[row * 32000 + col] = acc[mt][nt][r] + dec_b[col];
      }
}

// ---------- host ----------
extern "C" void kernel_launch(void* const* d_in, const int* in_sizes, int n_in,
                              void* d_out, int out_size, void* d_ws, size_t ws_size,
                              hipStream_t stream) {
  const int*   text    = (const int*)d_in[0];
  const int*   tstep   = (const int*)d_in[1];
  const float* U       = (const float*)d_in[2];
  const float* trans_W = (const float*)d_in[3];
  const float* trans_b = (const float*)d_in[4];
  const float* tc_W1   = (const float*)d_in[5];
  const float* tc_b1   = (const float*)d_in[6];
  const float* tc_W2   = (const float*)d_in[7];
  const float* tc_b2   = (const float*)d_in[8];
  const float* dw_W    = (const float*)d_in[9];
  const float* dw_b    = (const float*)d_in[10];
  const float* Wih0    = (const float*)d_in[11];
  const float* Whh0    = (const float*)d_in[12];
  const float* bih0    = (const float*)d_in[13];
  const float* bhh0    = (const float*)d_in[14];
  const float* Wih1    = (const float*)d_in[15];
  const float* Whh1    = (const float*)d_in[16];
  const float* bih1    = (const float*)d_in[17];
  const float* bhh1    = (const float*)d_in[18];
  const float* dec_W   = (const float*)d_in[19];
  const float* dec_b   = (const float*)d_in[20];

  char* ws = (char*)d_ws;
  float* ht            = (float*)(ws + 0);                 //  8 KB [32][64]
  float* vbias         = (float*)(ws + 8192);              //  8 KB [32][64]
  float* Mbuf          = (float*)(ws + 16384);             //  4 MB [32][64][512]
  unsigned short* vecb = (unsigned short*)(ws + 4210688);  // 512 KB bf16 [4096][64]
  float* A0            = (float*)(ws + 4734976);           //  1 MB [4096][64]
  float* c0            = (float*)(ws + 5783552);           // 16 KB [4096]
  unsigned short* h0b  = (unsigned short*)(ws + 5799936);  // 128 KB bf16 2x[32][1024]
  unsigned short* h1b  = (unsigned short*)(ws + 5931008);  // 128 KB
  unsigned short* o0   = (unsigned short*)(ws + 6062080);  //  8 MB bf16 [128][32][1024]
  unsigned short* o1   = (unsigned short*)(ws + 14450688); //  8 MB
  unsigned int* flag0  = (unsigned int*)(ws + 22839296);   // 256 B [64] (512 B region)
  unsigned int* flag1  = (unsigned int*)(ws + 22839808);   // 512 B [128]

  // h buffers and step flags must start zeroed (ws is poisoned 0xAA)
  (void)hipMemsetAsync(ws + 5799936, 0, 262144, stream);
  (void)hipMemsetAsync(ws + 22839296, 0, 1024, stream);

  k_prep<<<32, 64, 0, stream>>>(tstep, tc_W1, tc_b1, tc_W2, tc_b2, trans_b, ht, vbias);
  k_M<<<dim3(64, 8), 512, 0, stream>>>(trans_W, ht, Mbuf);
  k_vec<<<dim3(32, 8), 256, 0, stream>>>(text, U, Mbuf, vbias, vecb);
  k_A0<<<64, 256, 0, stream>>>(Wih0, dw_W, dw_b, bih0, bhh0, A0, c0);

  k_lstm<<<192, 256, 0, stream>>>(vecb, A0, c0, Whh0, Wih1, Whh1, bih1, bhh1,
                                  h0b, h1b, o0, o1, flag0, flag1);

  k_dec<<<dim3(32, 250), 256, 0, stream>>>(o1, dec_W, dec_b, (float*)d_out);
}